// Round 2
// baseline (240.890 us; speedup 1.0000x reference)
//
#include <hip/hip_runtime.h>

#define I_DIM 1024
#define J_DIM 1024
#define H_DIM 32
#define INV_I1 (1.0f/1023.0f)
#define INV_J1 (1.0f/1023.0f)

// ws layout (float offsets)
#define WS_CW     0         // colsum(weight)            [1024]
#define WS_RW     1024      // rowsum(weight)            [1024]
#define WS_CH     2048      // colsum(hidden) (J*H)      [32768]
#define WS_PJ     67584     // per-j layer1 partial      [1024*10]
#define WS_QI     77824     // per-i layer1 partial      [1024*10]
#define WS_LOGITS 88064     // X @ new_weight            [1024*1024]
// Partials overlap the logits region (dead until k_gemm):
#define WS_RHP    88064     // rowsum_h partials [1024][8][32] = 262144
#define WS_WPART  (88064 + 262144)          // [npart][1024]
// hpart follows wpart: [npart][32768]

// ---------------------------------------------------------------------------
// Kernel 1: single pass over Hd (and W): block (p,c) reads rows [p*R,(p+1)*R)
// x col-chunk c (4096 floats). Produces: VGPR colsum partials -> hpart,
// per-row rowsum_h partials (shuffle-reduced) -> rhpart, W rowsums (c==0)
// -> ws[WS_RW], W colsum partials -> wpart.
// ---------------------------------------------------------------------------
__global__ __launch_bounds__(512) void k_red1(const float* __restrict__ W,
                                              const float* __restrict__ Hd,
                                              float* __restrict__ ws,
                                              float* __restrict__ hpart,
                                              float* __restrict__ wpart,
                                              float* __restrict__ rhpart,
                                              int npart) {
  __shared__ float4 s4[512];   // [rowInGroup(8)][wave(8)][lane<8]
  __shared__ float  s1[32];    // [rowInGroup(8)][wave<4]
  int t = threadIdx.x;
  int wv = t >> 6, lane = t & 63;
  int p = blockIdx.x >> 3, c = blockIdx.x & 7;
  int R = 1024 / npart;
  int i0 = p * R;
  float4 ca0 = make_float4(0.f,0.f,0.f,0.f);
  float4 ca1 = make_float4(0.f,0.f,0.f,0.f);
  float4 wca = make_float4(0.f,0.f,0.f,0.f);
  for (int g = 0; g < R; g += 8) {
    int G = (R < 8) ? R : 8;
    for (int r = 0; r < G; r++) {
      int i = i0 + g + r;
      const float4* rowc = (const float4*)(Hd + (size_t)i * 32768 + c * 4096);
      float4 v0 = rowc[t];
      float4 v1 = rowc[t + 512];
      ca0.x += v0.x; ca0.y += v0.y; ca0.z += v0.z; ca0.w += v0.w;
      ca1.x += v1.x; ca1.y += v1.y; ca1.z += v1.z; ca1.w += v1.w;
      float4 rs;
      rs.x = v0.x + v1.x; rs.y = v0.y + v1.y;
      rs.z = v0.z + v1.z; rs.w = v0.w + v1.w;
      #pragma unroll
      for (int off = 8; off <= 32; off <<= 1) {
        rs.x += __shfl_xor(rs.x, off, 64);
        rs.y += __shfl_xor(rs.y, off, 64);
        rs.z += __shfl_xor(rs.z, off, 64);
        rs.w += __shfl_xor(rs.w, off, 64);
      }
      if (lane < 8) s4[(r * 8 + wv) * 8 + lane] = rs;
      if (c == 0) {
        float wdot = 0.f;
        if (t < 256) {
          float4 wvv = ((const float4*)(W + (size_t)i * 1024))[t];
          wca.x += wvv.x; wca.y += wvv.y; wca.z += wvv.z; wca.w += wvv.w;
          wdot = wvv.x + wvv.y + wvv.z + wvv.w;
        }
        #pragma unroll
        for (int off = 1; off <= 32; off <<= 1) wdot += __shfl_xor(wdot, off, 64);
        if (wv < 4 && lane == 0) s1[r * 4 + wv] = wdot;
      }
    }
    __syncthreads();
    if (t < G * 8) {
      int r = t >> 3, ln = t & 7;
      float4 a = s4[(r * 8 + 0) * 8 + ln];
      #pragma unroll
      for (int w2 = 1; w2 < 8; w2++) {
        float4 b = s4[(r * 8 + w2) * 8 + ln];
        a.x += b.x; a.y += b.y; a.z += b.z; a.w += b.w;
      }
      int i = i0 + g + r;
      ((float4*)rhpart)[i * 64 + c * 8 + ln] = a;
    }
    if (c == 0 && t < G) {
      int i = i0 + g + t;
      ws[WS_RW + i] = s1[t * 4] + s1[t * 4 + 1] + s1[t * 4 + 2] + s1[t * 4 + 3];
    }
    __syncthreads();
  }
  float4* hp = (float4*)(hpart + (size_t)p * 32768 + c * 4096);
  hp[t] = ca0;
  hp[t + 512] = ca1;
  if (c == 0 && t < 256) ((float4*)(wpart + (size_t)p * 1024))[t] = wca;
}

// ---------------------------------------------------------------------------
// Kernel 2: fold colsum partials -> ws[WS_CH], ws[WS_CW]
// ---------------------------------------------------------------------------
__global__ __launch_bounds__(256) void k_red2(const float* __restrict__ hpart,
                                              const float* __restrict__ wpart,
                                              float* __restrict__ ws, int npart) {
  int b = blockIdx.x, t = threadIdx.x;
  if (b < 128) {
    int col = b * 256 + t;
    float acc = 0.f;
    for (int p = 0; p < npart; p++) acc += hpart[(size_t)p * 32768 + col];
    ws[WS_CH + col] = acc;
  } else {
    int col = (b - 128) * 256 + t;
    float acc = 0.f;
    for (int p = 0; p < npart; p++) acc += wpart[(size_t)p * 1024 + col];
    ws[WS_CW + col] = acc;
  }
}

// ---------------------------------------------------------------------------
// Kernel 3: per-j (Pj) and per-i (Qi, includes b1) layer-1 partials
// ---------------------------------------------------------------------------
__global__ __launch_bounds__(256) void k_pq(const float* __restrict__ W1,
                                            const float* __restrict__ b1,
                                            float* __restrict__ ws,
                                            const float* __restrict__ rhpart) {
  int gid = blockIdx.x * 256 + threadIdx.x;
  float out[10];
  if (gid < 1024) {
    int j = gid;
    float sc = ws[WS_CW + j] * INV_I1;
    #pragma unroll
    for (int q = 0; q < 10; q++) out[q] = sc * W1[10 + q];
    for (int k = 0; k < 32; k++) {
      float cc = ws[WS_CH + j * 32 + k] * INV_I1;
      #pragma unroll
      for (int q = 0; q < 10; q++) out[q] += cc * W1[(35 + k) * 10 + q];
    }
    #pragma unroll
    for (int q = 0; q < 10; q++) ws[WS_PJ + j * 10 + q] = out[q];
  } else {
    int i = gid - 1024;
    float rh[32];
    #pragma unroll
    for (int k = 0; k < 32; k++) rh[k] = 0.f;
    for (int c = 0; c < 8; c++) {
      #pragma unroll
      for (int k = 0; k < 32; k++) rh[k] += rhpart[i * 256 + c * 32 + k];
    }
    float sr = ws[WS_RW + i] * INV_J1;
    #pragma unroll
    for (int q = 0; q < 10; q++) out[q] = b1[q] + sr * W1[20 + q];
    for (int k = 0; k < 32; k++) {
      float cc = rh[k] * INV_J1;
      #pragma unroll
      for (int q = 0; q < 10; q++) out[q] += cc * W1[(67 + k) * 10 + q];
    }
    #pragma unroll
    for (int q = 0; q < 10; q++) ws[WS_QI + i * 10 + q] = out[q];
  }
}

// ---------------------------------------------------------------------------
// Kernel 4: per-cell MLP, LDS-staged coalesced I/O.
// Block = 256 cells (one i, 256 consecutive j). XOR-swizzled hbuf:
//   cell data float4 #m lives at slot cell*8 + ((m+cell)&7)   (bank-optimal
//   for both the linear copy and the per-thread row access).
// ---------------------------------------------------------------------------
__global__ __launch_bounds__(256) void k_mlp(
    const float* __restrict__ W, const float* __restrict__ Hd,
    const float* __restrict__ W1, const float* __restrict__ W2,
    const float* __restrict__ b2, const float* __restrict__ W3,
    const float* __restrict__ b3, const float* __restrict__ ws,
    float* __restrict__ newW, float* __restrict__ newH) {
  __shared__ __align__(16) float hbuf[8192];   // 32 KB
  __shared__ float pjl[256][11];
  __shared__ float Al[33][12];
  __shared__ float W2l[10][12];
  __shared__ float W3t[33][12];
  __shared__ float b3l[33];
  __shared__ float b2l[10];
  int t = threadIdx.x;
  int cell0 = blockIdx.x * 256;
  int i = blockIdx.x >> 2;
  int j0 = (blockIdx.x & 3) * 256;

  // --- coalesced global -> swizzled LDS (Hd tile) ---
  const float4* src = (const float4*)(Hd + (size_t)cell0 * 32);
  #pragma unroll
  for (int m = 0; m < 8; m++) {
    int s = t + 256 * m;
    float4 v = src[s];
    int cs = s >> 3, ms = s & 7;
    int slot = cs * 8 + ((ms + cs) & 7);
    *(float4*)&hbuf[slot * 4] = v;
  }
  // --- pj tile ---
  const float* pjsrc = ws + WS_PJ + (size_t)j0 * 10;
  #pragma unroll
  for (int m = 0; m < 10; m++) {
    int idx = t + 256 * m;
    pjl[idx / 10][idx % 10] = pjsrc[idx];
  }
  // --- combined weights ---
  for (int idx = t; idx < 330; idx += 256) {
    int r = idx / 10, q = idx - r * 10;
    float v;
    if (r == 0)
      v = W1[q] - W1[10 + q] * INV_I1 - W1[20 + q] * INV_J1;
    else
      v = W1[(2 + r) * 10 + q] - W1[(34 + r) * 10 + q] * INV_I1 - W1[(66 + r) * 10 + q] * INV_J1;
    Al[r][q] = v;
  }
  for (int idx = t; idx < 100; idx += 256) W2l[idx / 10][idx - (idx / 10) * 10] = W2[idx];
  for (int idx = t; idx < 330; idx += 256) { int q2 = idx / 33, o = idx - q2 * 33; W3t[o][q2] = W3[idx]; }
  if (t < 33) b3l[t] = b3[t];
  if (t < 10) b2l[t] = b2[t];
  __syncthreads();

  // --- own-cell registers ---
  float w0 = W[cell0 + t];
  float qi[10];
  #pragma unroll
  for (int q = 0; q < 10; q++) qi[q] = ws[WS_QI + i * 10 + q];

  float h[32];
  #pragma unroll
  for (int m = 0; m < 8; m++) {
    int slot = t * 8 + ((m + t) & 7);
    float4 v = *(const float4*)&hbuf[slot * 4];
    h[m * 4 + 0] = v.x; h[m * 4 + 1] = v.y; h[m * 4 + 2] = v.z; h[m * 4 + 3] = v.w;
  }

  float z[10];
  #pragma unroll
  for (int q = 0; q < 10; q++) z[q] = pjl[t][q] + qi[q] + w0 * Al[0][q];
  #pragma unroll
  for (int k = 0; k < 32; k++) {
    #pragma unroll
    for (int q = 0; q < 10; q++) z[q] += h[k] * Al[k + 1][q];
  }
  #pragma unroll
  for (int q = 0; q < 10; q++) z[q] = fmaxf(z[q], 0.f);

  float y[10];
  #pragma unroll
  for (int q2 = 0; q2 < 10; q2++) y[q2] = b2l[q2];
  #pragma unroll
  for (int q = 0; q < 10; q++) {
    #pragma unroll
    for (int q2 = 0; q2 < 10; q2++) y[q2] += z[q] * W2l[q][q2];
  }
  #pragma unroll
  for (int q2 = 0; q2 < 10; q2++) y[q2] = fmaxf(y[q2], 0.f);

  float u = b3l[0];
  #pragma unroll
  for (int q2 = 0; q2 < 10; q2++) u += y[q2] * W3t[0][q2];
  newW[cell0 + t] = w0 + u;

  #pragma unroll
  for (int o = 1; o < 33; o++) {
    float a = b3l[o];
    #pragma unroll
    for (int q2 = 0; q2 < 10; q2++) a += y[q2] * W3t[o][q2];
    h[o - 1] += a;
  }

  // --- updated h -> swizzled LDS -> coalesced global ---
  #pragma unroll
  for (int m = 0; m < 8; m++) {
    int slot = t * 8 + ((m + t) & 7);
    *(float4*)&hbuf[slot * 4] = make_float4(h[m * 4], h[m * 4 + 1], h[m * 4 + 2], h[m * 4 + 3]);
  }
  __syncthreads();
  float4* dst = (float4*)(newH + (size_t)cell0 * 32);
  #pragma unroll
  for (int m = 0; m < 8; m++) {
    int s = t + 256 * m;
    int cs = s >> 3, ms = s & 7;
    int slot = cs * 8 + ((ms + cs) & 7);
    dst[s] = *(const float4*)&hbuf[slot * 4];
  }
}

// ---------------------------------------------------------------------------
// Kernel 5: f32 GEMM  logits = X(1024x1024) @ newW(1024x1024)
// ---------------------------------------------------------------------------
__global__ __launch_bounds__(256) void k_gemm(const float* __restrict__ A,
                                              const float* __restrict__ B,
                                              float* __restrict__ C) {
  __shared__ float As[16][68];
  __shared__ float Bs[16][68];
  int t = threadIdx.x;
  int bm = blockIdx.y, bn = blockIdx.x;
  int ar = t >> 2, ak = (t & 3) << 2;
  int bk = t >> 4, bnc = (t & 15) << 2;
  int tm = (t >> 4) << 2, tn = (t & 15) << 2;
  const float* Ap = A + (bm * 64 + ar) * 1024 + ak;
  const float* Bp = B + bk * 1024 + bn * 64 + bnc;
  float acc[4][4] = {};
  float4 av = *(const float4*)Ap;
  float4 bv = *(const float4*)Bp;
  for (int k0 = 0; k0 < 1024; k0 += 16) {
    __syncthreads();
    As[ak + 0][ar] = av.x; As[ak + 1][ar] = av.y;
    As[ak + 2][ar] = av.z; As[ak + 3][ar] = av.w;
    *(float4*)&Bs[bk][bnc] = bv;
    __syncthreads();
    if (k0 + 16 < 1024) {
      av = *(const float4*)(Ap + k0 + 16);
      bv = *(const float4*)(Bp + (k0 + 16) * 1024);
    }
    #pragma unroll
    for (int kk = 0; kk < 16; kk++) {
      float4 a4 = *(const float4*)&As[kk][tm];
      float4 b4 = *(const float4*)&Bs[kk][tn];
      acc[0][0] += a4.x * b4.x; acc[0][1] += a4.x * b4.y; acc[0][2] += a4.x * b4.z; acc[0][3] += a4.x * b4.w;
      acc[1][0] += a4.y * b4.x; acc[1][1] += a4.y * b4.y; acc[1][2] += a4.y * b4.z; acc[1][3] += a4.y * b4.w;
      acc[2][0] += a4.z * b4.x; acc[2][1] += a4.z * b4.y; acc[2][2] += a4.z * b4.z; acc[2][3] += a4.z * b4.w;
      acc[3][0] += a4.w * b4.x; acc[3][1] += a4.w * b4.y; acc[3][2] += a4.w * b4.z; acc[3][3] += a4.w * b4.w;
    }
  }
  #pragma unroll
  for (int r = 0; r < 4; r++) {
    *(float4*)&C[(bm * 64 + tm + r) * 1024 + bn * 64 + tn] =
        make_float4(acc[r][0], acc[r][1], acc[r][2], acc[r][3]);
  }
}

// ---------------------------------------------------------------------------
// Kernel 6: row softmax
// ---------------------------------------------------------------------------
__global__ __launch_bounds__(256) void k_softmax(const float* __restrict__ L,
                                                 float* __restrict__ P) {
  __shared__ float sm[4], ss[4];
  int r = blockIdx.x, t = threadIdx.x;
  const float* row = L + r * 1024;
  float v0 = row[t], v1 = row[t + 256], v2 = row[t + 512], v3 = row[t + 768];
  float m = fmaxf(fmaxf(v0, v1), fmaxf(v2, v3));
  #pragma unroll
  for (int off = 32; off > 0; off >>= 1) m = fmaxf(m, __shfl_xor(m, off, 64));
  int wv = t >> 6, lane = t & 63;
  if (lane == 0) sm[wv] = m;
  __syncthreads();
  m = fmaxf(fmaxf(sm[0], sm[1]), fmaxf(sm[2], sm[3]));
  float e0 = expf(v0 - m), e1 = expf(v1 - m), e2 = expf(v2 - m), e3 = expf(v3 - m);
  float s = e0 + e1 + e2 + e3;
  #pragma unroll
  for (int off = 32; off > 0; off >>= 1) s += __shfl_xor(s, off, 64);
  if (lane == 0) ss[wv] = s;
  __syncthreads();
  s = ss[0] + ss[1] + ss[2] + ss[3];
  float inv = 1.0f / s;
  float* prow = P + r * 1024;
  prow[t] = e0 * inv; prow[t + 256] = e1 * inv;
  prow[t + 512] = e2 * inv; prow[t + 768] = e3 * inv;
}

extern "C" void kernel_launch(void* const* d_in, const int* in_sizes, int n_in,
                              void* d_out, int out_size, void* d_ws, size_t ws_size,
                              hipStream_t stream) {
  const float* X  = (const float*)d_in[0];
  const float* W  = (const float*)d_in[1];
  const float* Hd = (const float*)d_in[2];
  const float* W1 = (const float*)d_in[3];
  const float* b1 = (const float*)d_in[4];
  const float* W2 = (const float*)d_in[5];
  const float* b2 = (const float*)d_in[6];
  const float* W3 = (const float*)d_in[7];
  const float* b3 = (const float*)d_in[8];
  float* out   = (float*)d_out;
  float* probs = out;
  float* newW  = out + 1024 * 1024;
  float* newH  = out + 2 * 1024 * 1024;
  float* ws = (float*)d_ws;

  // Choose npart (col-sum partial count) from available scratch.
  size_t wsf = ws_size / 4;
  int npart = 8;
  while (npart < 256 && (size_t)WS_WPART + (size_t)(npart * 2) * 33792ull <= wsf)
    npart *= 2;
  float* rhpart = ws + WS_RHP;
  float* wpart  = ws + WS_WPART;
  float* hpart  = wpart + (size_t)npart * 1024;

  k_red1<<<npart * 8, 512, 0, stream>>>(W, Hd, ws, hpart, wpart, rhpart, npart);
  k_red2<<<132, 256, 0, stream>>>(hpart, wpart, ws, npart);
  k_pq<<<8, 256, 0, stream>>>(W1, b1, ws, rhpart);
  k_mlp<<<4096, 256, 0, stream>>>(W, Hd, W1, W2, b2, W3, b3, ws, newW, newH);
  k_gemm<<<dim3(16, 16), 256, 0, stream>>>(X, newW, ws + WS_LOGITS);
  k_softmax<<<1024, 256, 0, stream>>>(ws + WS_LOGITS, probs);
}

// Round 3
// 170.200 us; speedup vs baseline: 1.4153x; 1.4153x over previous
//
#include <hip/hip_runtime.h>

#define I_DIM 1024
#define J_DIM 1024
#define INV_I1 (1.0f/1023.0f)
#define INV_J1 (1.0f/1023.0f)

// ws layout (float offsets)
#define WS_CW     0                  // colsum(weight)           [1024]
#define WS_RW     1024               // rowsum(weight)           [1024]
#define WS_CH     2048               // colsum(hidden) (J*H)     [32768]
#define WS_PJT    34816              // per-j layer1 partial, TRANSPOSED [10][1024]
#define WS_QI     45056              // per-i layer1 partial     [1024][10]
#define WS_CST    55296              // folded MLP constants     [~803]
#define WS_LOGITS 65536              // X @ new_weight           [1024*1024]
// Temporaries overlapping the logits region (dead before k_gemm):
#define WS_RHP    65536              // rowsum_h partials [1024][8][32] = 262144
#define WS_WCP    327680             // W colsum partials [16][1024] = 16384
#define WS_HPART  344064             // colsum_h partials [npart][32768]

// cst sub-layout: A[33][10] @0, W2[10][10] @330, W3t[33][10] @430, b2 @760, b3 @770

// ---------------------------------------------------------------------------
// Kernel 1: single pass over Hd. Block (p,c): rows [p*R,(p+1)*R) x col-chunk c
// (4096 floats). Register colsum partials -> hpart; per-row rowsum partials
// (shuffle-reduced) -> rhpart.
// ---------------------------------------------------------------------------
__global__ __launch_bounds__(512) void k_red1(const float* __restrict__ Hd,
                                              float* __restrict__ hpart,
                                              float* __restrict__ rhpart,
                                              int npart) {
  __shared__ float4 s4[512];   // [rowInGroup(8)][wave(8)][lane<8]
  int t = threadIdx.x;
  int wv = t >> 6, lane = t & 63;
  int p = blockIdx.x >> 3, c = blockIdx.x & 7;
  int R = 1024 / npart;        // multiple of 8 for npart<=128
  int i0 = p * R;
  float4 ca0 = make_float4(0.f,0.f,0.f,0.f);
  float4 ca1 = make_float4(0.f,0.f,0.f,0.f);
  for (int g = 0; g < R; g += 8) {
    #pragma unroll
    for (int r = 0; r < 8; r++) {
      int i = i0 + g + r;
      const float4* rowc = (const float4*)(Hd + (size_t)i * 32768 + c * 4096);
      float4 v0 = rowc[t];
      float4 v1 = rowc[t + 512];
      ca0.x += v0.x; ca0.y += v0.y; ca0.z += v0.z; ca0.w += v0.w;
      ca1.x += v1.x; ca1.y += v1.y; ca1.z += v1.z; ca1.w += v1.w;
      float4 rs;
      rs.x = v0.x + v1.x; rs.y = v0.y + v1.y;
      rs.z = v0.z + v1.z; rs.w = v0.w + v1.w;
      #pragma unroll
      for (int off = 8; off <= 32; off <<= 1) {
        rs.x += __shfl_xor(rs.x, off, 64);
        rs.y += __shfl_xor(rs.y, off, 64);
        rs.z += __shfl_xor(rs.z, off, 64);
        rs.w += __shfl_xor(rs.w, off, 64);
      }
      if (lane < 8) s4[(r * 8 + wv) * 8 + lane] = rs;
    }
    __syncthreads();
    if (t < 64) {
      int r = t >> 3, ln = t & 7;
      float4 a = s4[(r * 8 + 0) * 8 + ln];
      #pragma unroll
      for (int w2 = 1; w2 < 8; w2++) {
        float4 b = s4[(r * 8 + w2) * 8 + ln];
        a.x += b.x; a.y += b.y; a.z += b.z; a.w += b.w;
      }
      int i = i0 + g + r;
      ((float4*)rhpart)[i * 64 + c * 8 + ln] = a;
    }
    __syncthreads();
  }
  float4* hp = (float4*)(hpart + (size_t)p * 32768 + c * 4096);
  hp[t] = ca0;
  hp[t + 512] = ca1;
}

// ---------------------------------------------------------------------------
// Kernel 2: W reductions. b<128: rowsum (8 rows/block, shuffle);
// b in [128,144): colsum partials over 64-row stripes -> wcp[16][1024].
// ---------------------------------------------------------------------------
__global__ __launch_bounds__(256) void k_wred(const float* __restrict__ W,
                                              float* __restrict__ ws,
                                              float* __restrict__ wcp) {
  int b = blockIdx.x, t = threadIdx.x;
  if (b < 128) {
    int wv = t >> 6, lane = t & 63;
    #pragma unroll
    for (int rr = 0; rr < 2; rr++) {
      int row = b * 8 + wv * 2 + rr;
      float acc = 0.f;
      #pragma unroll
      for (int m = 0; m < 16; m++) acc += W[row * 1024 + lane + 64 * m];
      #pragma unroll
      for (int off = 32; off > 0; off >>= 1) acc += __shfl_down(acc, off, 64);
      if (lane == 0) ws[WS_RW + row] = acc;
    }
  } else {
    int p = b - 128;
    float a0 = 0.f, a1 = 0.f, a2 = 0.f, a3 = 0.f;
    for (int i = p * 64; i < p * 64 + 64; i++) {
      const float* row = W + (size_t)i * 1024;
      a0 += row[t]; a1 += row[t + 256]; a2 += row[t + 512]; a3 += row[t + 768];
    }
    wcp[p * 1024 + t] = a0;       wcp[p * 1024 + t + 256] = a1;
    wcp[p * 1024 + t + 512] = a2; wcp[p * 1024 + t + 768] = a3;
  }
}

// ---------------------------------------------------------------------------
// Kernel 3: fold colsum partials -> ws[WS_CH], ws[WS_CW]
// ---------------------------------------------------------------------------
__global__ __launch_bounds__(256) void k_red2(const float* __restrict__ hpart,
                                              const float* __restrict__ wcp,
                                              float* __restrict__ ws, int npart) {
  int b = blockIdx.x, t = threadIdx.x;
  if (b < 128) {
    int col = b * 256 + t;
    float acc = 0.f;
    for (int p = 0; p < npart; p++) acc += hpart[(size_t)p * 32768 + col];
    ws[WS_CH + col] = acc;
  } else {
    int col = (b - 128) * 256 + t;
    float acc = 0.f;
    #pragma unroll
    for (int p = 0; p < 16; p++) acc += wcp[p * 1024 + col];
    ws[WS_CW + col] = acc;
  }
}

// ---------------------------------------------------------------------------
// Kernel 4: Pj (transposed), Qi, and folded MLP constants (block 8)
// ---------------------------------------------------------------------------
__global__ __launch_bounds__(256) void k_pq(const float* __restrict__ W1,
                                            const float* __restrict__ b1,
                                            const float* __restrict__ W2,
                                            const float* __restrict__ b2,
                                            const float* __restrict__ W3,
                                            const float* __restrict__ b3,
                                            float* __restrict__ ws,
                                            const float* __restrict__ rhpart) {
  if (blockIdx.x == 8) {
    int t = threadIdx.x;
    for (int idx = t; idx < 330; idx += 256) {
      int r = idx / 10, q = idx - r * 10;
      float v;
      if (r == 0)
        v = W1[q] - W1[10 + q] * INV_I1 - W1[20 + q] * INV_J1;
      else
        v = W1[(2 + r) * 10 + q] - W1[(34 + r) * 10 + q] * INV_I1 - W1[(66 + r) * 10 + q] * INV_J1;
      ws[WS_CST + idx] = v;
    }
    for (int idx = t; idx < 100; idx += 256) ws[WS_CST + 330 + idx] = W2[idx];
    for (int idx = t; idx < 330; idx += 256) {
      int o = idx / 10, q2 = idx - o * 10;
      ws[WS_CST + 430 + idx] = W3[q2 * 33 + o];
    }
    if (t < 10) ws[WS_CST + 760 + t] = b2[t];
    if (t < 33) ws[WS_CST + 770 + t] = b3[t];
    return;
  }
  int gid = blockIdx.x * 256 + threadIdx.x;
  float out[10];
  if (gid < 1024) {
    int j = gid;
    float sc = ws[WS_CW + j] * INV_I1;
    #pragma unroll
    for (int q = 0; q < 10; q++) out[q] = sc * W1[10 + q];
    for (int k = 0; k < 32; k++) {
      float cc = ws[WS_CH + j * 32 + k] * INV_I1;
      #pragma unroll
      for (int q = 0; q < 10; q++) out[q] += cc * W1[(35 + k) * 10 + q];
    }
    #pragma unroll
    for (int q = 0; q < 10; q++) ws[WS_PJT + q * 1024 + j] = out[q];
  } else {
    int i = gid - 1024;
    float rh[32];
    #pragma unroll
    for (int k = 0; k < 32; k++) rh[k] = 0.f;
    for (int c = 0; c < 8; c++) {
      #pragma unroll
      for (int k = 0; k < 32; k++) rh[k] += rhpart[i * 256 + c * 32 + k];
    }
    float sr = ws[WS_RW + i] * INV_J1;
    #pragma unroll
    for (int q = 0; q < 10; q++) out[q] = b1[q] + sr * W1[20 + q];
    for (int k = 0; k < 32; k++) {
      float cc = rh[k] * INV_J1;
      #pragma unroll
      for (int q = 0; q < 10; q++) out[q] += cc * W1[(67 + k) * 10 + q];
    }
    #pragma unroll
    for (int q = 0; q < 10; q++) ws[WS_QI + i * 10 + q] = out[q];
  }
}

// ---------------------------------------------------------------------------
// Kernel 5: per-cell MLP. Hd tile staged via swizzled LDS (coalesced I/O);
// all MLP weights read via wave-uniform s_loads (cst) — no LDS in math path.
// ---------------------------------------------------------------------------
__global__ __launch_bounds__(256) void k_mlp(
    const float* __restrict__ W, const float* __restrict__ Hd,
    const float* __restrict__ ws,
    float* __restrict__ newW, float* __restrict__ newH) {
  __shared__ __align__(16) float hbuf[8192];   // 32 KB
  int t = threadIdx.x;
  int cell0 = blockIdx.x * 256;
  int i = blockIdx.x >> 2;
  int j0 = (blockIdx.x & 3) * 256;
  const float* cst = ws + WS_CST;

  // coalesced global -> swizzled LDS (Hd tile)
  const float4* src = (const float4*)(Hd + (size_t)cell0 * 32);
  #pragma unroll
  for (int m = 0; m < 8; m++) {
    int s = t + 256 * m;
    float4 v = src[s];
    int cs = s >> 3, ms = s & 7;
    int slot = cs * 8 + ((ms + cs) & 7);
    *(float4*)&hbuf[slot * 4] = v;
  }
  float w0 = W[cell0 + t];
  float pj[10];
  #pragma unroll
  for (int q = 0; q < 10; q++) pj[q] = ws[WS_PJT + q * 1024 + j0 + t];
  float qv[10];
  #pragma unroll
  for (int q = 0; q < 10; q++) qv[q] = ws[WS_QI + i * 10 + q];  // uniform -> s_load
  __syncthreads();

  float h[32];
  #pragma unroll
  for (int m = 0; m < 8; m++) {
    int slot = t * 8 + ((m + t) & 7);
    float4 v = *(const float4*)&hbuf[slot * 4];
    h[m * 4 + 0] = v.x; h[m * 4 + 1] = v.y; h[m * 4 + 2] = v.z; h[m * 4 + 3] = v.w;
  }

  float z[10];
  #pragma unroll
  for (int q = 0; q < 10; q++) z[q] = pj[q] + qv[q] + w0 * cst[q];
  #pragma unroll
  for (int k = 0; k < 32; k++) {
    #pragma unroll
    for (int q = 0; q < 10; q++) z[q] += h[k] * cst[(k + 1) * 10 + q];
  }
  #pragma unroll
  for (int q = 0; q < 10; q++) z[q] = fmaxf(z[q], 0.f);

  float y[10];
  #pragma unroll
  for (int q2 = 0; q2 < 10; q2++) y[q2] = cst[760 + q2];
  #pragma unroll
  for (int q = 0; q < 10; q++) {
    #pragma unroll
    for (int q2 = 0; q2 < 10; q2++) y[q2] += z[q] * cst[330 + q * 10 + q2];
  }
  #pragma unroll
  for (int q2 = 0; q2 < 10; q2++) y[q2] = fmaxf(y[q2], 0.f);

  float u = cst[770];
  #pragma unroll
  for (int q2 = 0; q2 < 10; q2++) u += y[q2] * cst[430 + q2];
  newW[cell0 + t] = w0 + u;

  #pragma unroll
  for (int o = 1; o < 33; o++) {
    float a = cst[770 + o];
    #pragma unroll
    for (int q2 = 0; q2 < 10; q2++) a += y[q2] * cst[430 + o * 10 + q2];
    h[o - 1] += a;
  }

  #pragma unroll
  for (int m = 0; m < 8; m++) {
    int slot = t * 8 + ((m + t) & 7);
    *(float4*)&hbuf[slot * 4] = make_float4(h[m * 4], h[m * 4 + 1], h[m * 4 + 2], h[m * 4 + 3]);
  }
  __syncthreads();
  float4* dst = (float4*)(newH + (size_t)cell0 * 32);
  #pragma unroll
  for (int m = 0; m < 8; m++) {
    int s = t + 256 * m;
    int cs = s >> 3, ms = s & 7;
    int slot = cs * 8 + ((ms + cs) & 7);
    dst[s] = *(const float4*)&hbuf[slot * 4];
  }
}

// ---------------------------------------------------------------------------
// Kernel 6: f32 GEMM  logits = X(1024x1024) @ newW(1024x1024)
// ---------------------------------------------------------------------------
__global__ __launch_bounds__(256) void k_gemm(const float* __restrict__ A,
                                              const float* __restrict__ B,
                                              float* __restrict__ C) {
  __shared__ float As[16][68];
  __shared__ float Bs[16][68];
  int t = threadIdx.x;
  int bm = blockIdx.y, bn = blockIdx.x;
  int ar = t >> 2, ak = (t & 3) << 2;
  int bk = t >> 4, bnc = (t & 15) << 2;
  int tm = (t >> 4) << 2, tn = (t & 15) << 2;
  const float* Ap = A + (bm * 64 + ar) * 1024 + ak;
  const float* Bp = B + bk * 1024 + bn * 64 + bnc;
  float acc[4][4] = {};
  float4 av = *(const float4*)Ap;
  float4 bv = *(const float4*)Bp;
  for (int k0 = 0; k0 < 1024; k0 += 16) {
    __syncthreads();
    As[ak + 0][ar] = av.x; As[ak + 1][ar] = av.y;
    As[ak + 2][ar] = av.z; As[ak + 3][ar] = av.w;
    *(float4*)&Bs[bk][bnc] = bv;
    __syncthreads();
    if (k0 + 16 < 1024) {
      av = *(const float4*)(Ap + k0 + 16);
      bv = *(const float4*)(Bp + (k0 + 16) * 1024);
    }
    #pragma unroll
    for (int kk = 0; kk < 16; kk++) {
      float4 a4 = *(const float4*)&As[kk][tm];
      float4 b4 = *(const float4*)&Bs[kk][tn];
      acc[0][0] += a4.x * b4.x; acc[0][1] += a4.x * b4.y; acc[0][2] += a4.x * b4.z; acc[0][3] += a4.x * b4.w;
      acc[1][0] += a4.y * b4.x; acc[1][1] += a4.y * b4.y; acc[1][2] += a4.y * b4.z; acc[1][3] += a4.y * b4.w;
      acc[2][0] += a4.z * b4.x; acc[2][1] += a4.z * b4.y; acc[2][2] += a4.z * b4.z; acc[2][3] += a4.z * b4.w;
      acc[3][0] += a4.w * b4.x; acc[3][1] += a4.w * b4.y; acc[3][2] += a4.w * b4.z; acc[3][3] += a4.w * b4.w;
    }
  }
  #pragma unroll
  for (int r = 0; r < 4; r++) {
    *(float4*)&C[(bm * 64 + tm + r) * 1024 + bn * 64 + tn] =
        make_float4(acc[r][0], acc[r][1], acc[r][2], acc[r][3]);
  }
}

// ---------------------------------------------------------------------------
// Kernel 7: row softmax
// ---------------------------------------------------------------------------
__global__ __launch_bounds__(256) void k_softmax(const float* __restrict__ L,
                                                 float* __restrict__ P) {
  __shared__ float sm[4], ss[4];
  int r = blockIdx.x, t = threadIdx.x;
  const float* row = L + r * 1024;
  float v0 = row[t], v1 = row[t + 256], v2 = row[t + 512], v3 = row[t + 768];
  float m = fmaxf(fmaxf(v0, v1), fmaxf(v2, v3));
  #pragma unroll
  for (int off = 32; off > 0; off >>= 1) m = fmaxf(m, __shfl_xor(m, off, 64));
  int wv = t >> 6, lane = t & 63;
  if (lane == 0) sm[wv] = m;
  __syncthreads();
  m = fmaxf(fmaxf(sm[0], sm[1]), fmaxf(sm[2], sm[3]));
  float e0 = expf(v0 - m), e1 = expf(v1 - m), e2 = expf(v2 - m), e3 = expf(v3 - m);
  float s = e0 + e1 + e2 + e3;
  #pragma unroll
  for (int off = 32; off > 0; off >>= 1) s += __shfl_xor(s, off, 64);
  if (lane == 0) ss[wv] = s;
  __syncthreads();
  s = ss[0] + ss[1] + ss[2] + ss[3];
  float inv = 1.0f / s;
  float* prow = P + r * 1024;
  prow[t] = e0 * inv; prow[t + 256] = e1 * inv;
  prow[t + 512] = e2 * inv; prow[t + 768] = e3 * inv;
}

extern "C" void kernel_launch(void* const* d_in, const int* in_sizes, int n_in,
                              void* d_out, int out_size, void* d_ws, size_t ws_size,
                              hipStream_t stream) {
  const float* X  = (const float*)d_in[0];
  const float* W  = (const float*)d_in[1];
  const float* Hd = (const float*)d_in[2];
  const float* W1 = (const float*)d_in[3];
  const float* b1 = (const float*)d_in[4];
  const float* W2 = (const float*)d_in[5];
  const float* b2 = (const float*)d_in[6];
  const float* W3 = (const float*)d_in[7];
  const float* b3 = (const float*)d_in[8];
  float* out   = (float*)d_out;
  float* probs = out;
  float* newW  = out + 1024 * 1024;
  float* newH  = out + 2 * 1024 * 1024;
  float* ws = (float*)d_ws;

  // npart: largest in {8..64} whose partials fit in ws (correct check:
  // region END must fit).
  size_t wsf = ws_size / 4;
  int npart = 64;
  while (npart > 8 && (size_t)WS_HPART + (size_t)npart * 32768ull > wsf) npart >>= 1;
  float* rhpart = ws + WS_RHP;
  float* wcp    = ws + WS_WCP;
  float* hpart  = ws + WS_HPART;

  k_red1<<<npart * 8, 512, 0, stream>>>(Hd, hpart, rhpart, npart);
  k_wred<<<144, 256, 0, stream>>>(W, ws, wcp);
  k_red2<<<132, 256, 0, stream>>>(hpart, wcp, ws, npart);
  k_pq<<<9, 256, 0, stream>>>(W1, b1, W2, b2, W3, b3, ws, rhpart);
  k_mlp<<<4096, 256, 0, stream>>>(W, Hd, ws, newW, newH);
  k_gemm<<<dim3(16, 16), 256, 0, stream>>>(X, newW, ws + WS_LOGITS);
  k_softmax<<<1024, 256, 0, stream>>>(ws + WS_LOGITS, probs);
}

// Round 4
// 157.143 us; speedup vs baseline: 1.5329x; 1.0831x over previous
//
#include <hip/hip_runtime.h>

#define INV_I1 (1.0f/1023.0f)
#define INV_J1 (1.0f/1023.0f)

// ws layout (float offsets)
#define WS_CW     0                  // colsum(weight)           [1024]
#define WS_RW     1024               // rowsum(weight)           [1024]
#define WS_CH     2048               // colsum(hidden) (J*H)     [32768]
#define WS_PJT    34816              // per-j layer1 partial, TRANSPOSED [10][1024]
#define WS_QI     45056              // per-i layer1 partial     [1024][10]
#define WS_CST    55296              // folded MLP constants     [~803]
#define WS_LOGITS 65536              // X @ new_weight           [1024*1024]
// Temporaries overlapping the logits region (dead before k_gemm):
#define WS_RHP    65536              // rowsum_h partials [1024][8][32] = 262144
#define WS_WCP    327680             // W colsum partials [16][1024] = 16384
#define WS_HPART  344064             // colsum_h partials [npart][32768]
// XB / WT (bf16 hi+lo planes, 1M ushorts each plane) follow HPART at runtime.

typedef __attribute__((ext_vector_type(8))) short bf16x8;
typedef __attribute__((ext_vector_type(4))) float f32x4;

__device__ inline ushort bf16_rne(float x) {
  union { float f; unsigned u; } v; v.f = x;
  unsigned r = v.u + 0x7fffu + ((v.u >> 16) & 1u);
  return (ushort)(r >> 16);
}
__device__ inline float bf16_tof(ushort h) {
  union { unsigned u; float f; } c; c.u = ((unsigned)h) << 16;
  return c.f;
}

// ---------------------------------------------------------------------------
// Kernel 1: single pass over Hd. Block (p,c): rows [p*R,(p+1)*R) x col-chunk c
// (4096 floats). Register colsum partials -> hpart; per-row rowsum partials
// (shuffle-reduced) -> rhpart.
// ---------------------------------------------------------------------------
__global__ __launch_bounds__(512) void k_red1(const float* __restrict__ Hd,
                                              float* __restrict__ hpart,
                                              float* __restrict__ rhpart,
                                              int npart) {
  __shared__ float4 s4[512];
  int t = threadIdx.x;
  int wv = t >> 6, lane = t & 63;
  int p = blockIdx.x >> 3, c = blockIdx.x & 7;
  int R = 1024 / npart;
  int i0 = p * R;
  float4 ca0 = make_float4(0.f,0.f,0.f,0.f);
  float4 ca1 = make_float4(0.f,0.f,0.f,0.f);
  for (int g = 0; g < R; g += 8) {
    #pragma unroll
    for (int r = 0; r < 8; r++) {
      int i = i0 + g + r;
      const float4* rowc = (const float4*)(Hd + (size_t)i * 32768 + c * 4096);
      float4 v0 = rowc[t];
      float4 v1 = rowc[t + 512];
      ca0.x += v0.x; ca0.y += v0.y; ca0.z += v0.z; ca0.w += v0.w;
      ca1.x += v1.x; ca1.y += v1.y; ca1.z += v1.z; ca1.w += v1.w;
      float4 rs;
      rs.x = v0.x + v1.x; rs.y = v0.y + v1.y;
      rs.z = v0.z + v1.z; rs.w = v0.w + v1.w;
      #pragma unroll
      for (int off = 8; off <= 32; off <<= 1) {
        rs.x += __shfl_xor(rs.x, off, 64);
        rs.y += __shfl_xor(rs.y, off, 64);
        rs.z += __shfl_xor(rs.z, off, 64);
        rs.w += __shfl_xor(rs.w, off, 64);
      }
      if (lane < 8) s4[(r * 8 + wv) * 8 + lane] = rs;
    }
    __syncthreads();
    if (t < 64) {
      int r = t >> 3, ln = t & 7;
      float4 a = s4[(r * 8 + 0) * 8 + ln];
      #pragma unroll
      for (int w2 = 1; w2 < 8; w2++) {
        float4 b = s4[(r * 8 + w2) * 8 + ln];
        a.x += b.x; a.y += b.y; a.z += b.z; a.w += b.w;
      }
      int i = i0 + g + r;
      ((float4*)rhpart)[i * 64 + c * 8 + ln] = a;
    }
    __syncthreads();
  }
  float4* hp = (float4*)(hpart + (size_t)p * 32768 + c * 4096);
  hp[t] = ca0;
  hp[t + 512] = ca1;
}

// ---------------------------------------------------------------------------
// Kernel 2: W reductions + X bf16 hi/lo split.
//  b<128: W rowsum; b in [128,144): W colsum partials; b>=144: X split.
// ---------------------------------------------------------------------------
__global__ __launch_bounds__(256) void k_wred(const float* __restrict__ W,
                                              const float* __restrict__ X,
                                              float* __restrict__ ws,
                                              float* __restrict__ wcp,
                                              ushort* __restrict__ Xb) {
  int b = blockIdx.x, t = threadIdx.x;
  if (b < 128) {
    int wv = t >> 6, lane = t & 63;
    #pragma unroll
    for (int rr = 0; rr < 2; rr++) {
      int row = b * 8 + wv * 2 + rr;
      float acc = 0.f;
      #pragma unroll
      for (int m = 0; m < 16; m++) acc += W[row * 1024 + lane + 64 * m];
      #pragma unroll
      for (int off = 32; off > 0; off >>= 1) acc += __shfl_down(acc, off, 64);
      if (lane == 0) ws[WS_RW + row] = acc;
    }
  } else if (b < 144) {
    int p = b - 128;
    float a0 = 0.f, a1 = 0.f, a2 = 0.f, a3 = 0.f;
    for (int i = p * 64; i < p * 64 + 64; i++) {
      const float* row = W + (size_t)i * 1024;
      a0 += row[t]; a1 += row[t + 256]; a2 += row[t + 512]; a3 += row[t + 768];
    }
    wcp[p * 1024 + t] = a0;       wcp[p * 1024 + t + 256] = a1;
    wcp[p * 1024 + t + 512] = a2; wcp[p * 1024 + t + 768] = a3;
  } else {
    // X split: 512 blocks, 8 floats/thread
    int g = (b - 144) * 256 + t;
    float4 v0 = ((const float4*)X)[g * 2];
    float4 v1 = ((const float4*)X)[g * 2 + 1];
    float xs[8] = {v0.x, v0.y, v0.z, v0.w, v1.x, v1.y, v1.z, v1.w};
    ushort hi[8], lo[8];
    #pragma unroll
    for (int e = 0; e < 8; e++) {
      hi[e] = bf16_rne(xs[e]);
      lo[e] = bf16_rne(xs[e] - bf16_tof(hi[e]));
    }
    ((uint4*)Xb)[g] = *(uint4*)hi;
    ((uint4*)(Xb + 1048576))[g] = *(uint4*)lo;
  }
}

// ---------------------------------------------------------------------------
// Kernel 3: fold colsum partials -> CH/CW, then Pj (same block), Qi, cst.
//  b<128: CH cols [b*256,(b+1)*256) + CW[j], Pj for j in [b*8,(b+1)*8)
//  b in [128,132): Qi for 256 i each
//  b==132: folded MLP constants
// ---------------------------------------------------------------------------
__global__ __launch_bounds__(256) void k_red2pq(const float* __restrict__ hpart,
                                                const float* __restrict__ wcp,
                                                const float* __restrict__ rhpart,
                                                const float* __restrict__ W1,
                                                const float* __restrict__ b1,
                                                const float* __restrict__ W2,
                                                const float* __restrict__ b2,
                                                const float* __restrict__ W3,
                                                const float* __restrict__ b3,
                                                float* __restrict__ ws, int npart) {
  int b = blockIdx.x, t = threadIdx.x;
  if (b < 128) {
    __shared__ float chl[256];
    __shared__ float cwl[8];
    int col = b * 256 + t;
    float acc = 0.f;
    for (int p = 0; p < npart; p++) acc += hpart[(size_t)p * 32768 + col];
    ws[WS_CH + col] = acc;
    chl[t] = acc;
    if (t < 8) {
      int j = b * 8 + t;
      float a = 0.f;
      #pragma unroll
      for (int p = 0; p < 16; p++) a += wcp[p * 1024 + j];
      ws[WS_CW + j] = a;
      cwl[t] = a;
    }
    __syncthreads();
    if (t < 80) {
      int jj = t / 10, q = t - jj * 10;
      int j = b * 8 + jj;
      float o = cwl[jj] * INV_I1 * W1[10 + q];
      for (int k = 0; k < 32; k++)
        o += chl[jj * 32 + k] * INV_I1 * W1[(35 + k) * 10 + q];
      ws[WS_PJT + q * 1024 + j] = o;
    }
  } else if (b < 132) {
    int i = (b - 128) * 256 + t;
    float rh[32];
    #pragma unroll
    for (int k = 0; k < 32; k++) rh[k] = 0.f;
    for (int c = 0; c < 8; c++) {
      #pragma unroll
      for (int k = 0; k < 32; k++) rh[k] += rhpart[i * 256 + c * 32 + k];
    }
    float sr = ws[WS_RW + i] * INV_J1;
    float out[10];
    #pragma unroll
    for (int q = 0; q < 10; q++) out[q] = b1[q] + sr * W1[20 + q];
    for (int k = 0; k < 32; k++) {
      float cc = rh[k] * INV_J1;
      #pragma unroll
      for (int q = 0; q < 10; q++) out[q] += cc * W1[(67 + k) * 10 + q];
    }
    #pragma unroll
    for (int q = 0; q < 10; q++) ws[WS_QI + i * 10 + q] = out[q];
  } else {
    for (int idx = t; idx < 330; idx += 256) {
      int r = idx / 10, q = idx - r * 10;
      float v;
      if (r == 0)
        v = W1[q] - W1[10 + q] * INV_I1 - W1[20 + q] * INV_J1;
      else
        v = W1[(2 + r) * 10 + q] - W1[(34 + r) * 10 + q] * INV_I1 - W1[(66 + r) * 10 + q] * INV_J1;
      ws[WS_CST + idx] = v;
    }
    for (int idx = t; idx < 100; idx += 256) ws[WS_CST + 330 + idx] = W2[idx];
    for (int idx = t; idx < 330; idx += 256) {
      int o = idx / 10, q2 = idx - o * 10;
      ws[WS_CST + 430 + idx] = W3[q2 * 33 + o];
    }
    if (t < 10) ws[WS_CST + 760 + t] = b2[t];
    if (t < 33) ws[WS_CST + 770 + t] = b3[t];
  }
}

// ---------------------------------------------------------------------------
// Kernel 4: per-cell MLP. Hd tile via swizzled LDS (coalesced I/O); all MLP
// weights via wave-uniform s_loads from ws cst.
// ---------------------------------------------------------------------------
__global__ __launch_bounds__(256) void k_mlp(
    const float* __restrict__ W, const float* __restrict__ Hd,
    const float* __restrict__ ws,
    float* __restrict__ newW, float* __restrict__ newH) {
  __shared__ __align__(16) float hbuf[8192];
  int t = threadIdx.x;
  int cell0 = blockIdx.x * 256;
  int i = blockIdx.x >> 2;
  int j0 = (blockIdx.x & 3) * 256;
  const float* cst = ws + WS_CST;

  const float4* src = (const float4*)(Hd + (size_t)cell0 * 32);
  #pragma unroll
  for (int m = 0; m < 8; m++) {
    int s = t + 256 * m;
    float4 v = src[s];
    int cs = s >> 3, ms = s & 7;
    int slot = cs * 8 + ((ms + cs) & 7);
    *(float4*)&hbuf[slot * 4] = v;
  }
  float w0 = W[cell0 + t];
  float pj[10];
  #pragma unroll
  for (int q = 0; q < 10; q++) pj[q] = ws[WS_PJT + q * 1024 + j0 + t];
  float qv[10];
  #pragma unroll
  for (int q = 0; q < 10; q++) qv[q] = ws[WS_QI + i * 10 + q];
  __syncthreads();

  float h[32];
  #pragma unroll
  for (int m = 0; m < 8; m++) {
    int slot = t * 8 + ((m + t) & 7);
    float4 v = *(const float4*)&hbuf[slot * 4];
    h[m * 4 + 0] = v.x; h[m * 4 + 1] = v.y; h[m * 4 + 2] = v.z; h[m * 4 + 3] = v.w;
  }

  float z[10];
  #pragma unroll
  for (int q = 0; q < 10; q++) z[q] = pj[q] + qv[q] + w0 * cst[q];
  #pragma unroll
  for (int k = 0; k < 32; k++) {
    #pragma unroll
    for (int q = 0; q < 10; q++) z[q] += h[k] * cst[(k + 1) * 10 + q];
  }
  #pragma unroll
  for (int q = 0; q < 10; q++) z[q] = fmaxf(z[q], 0.f);

  float y[10];
  #pragma unroll
  for (int q2 = 0; q2 < 10; q2++) y[q2] = cst[760 + q2];
  #pragma unroll
  for (int q = 0; q < 10; q++) {
    #pragma unroll
    for (int q2 = 0; q2 < 10; q2++) y[q2] += z[q] * cst[330 + q * 10 + q2];
  }
  #pragma unroll
  for (int q2 = 0; q2 < 10; q2++) y[q2] = fmaxf(y[q2], 0.f);

  float u = cst[770];
  #pragma unroll
  for (int q2 = 0; q2 < 10; q2++) u += y[q2] * cst[430 + q2];
  newW[cell0 + t] = w0 + u;

  #pragma unroll
  for (int o = 1; o < 33; o++) {
    float a = cst[770 + o];
    #pragma unroll
    for (int q2 = 0; q2 < 10; q2++) a += y[q2] * cst[430 + o * 10 + q2];
    h[o - 1] += a;
  }

  #pragma unroll
  for (int m = 0; m < 8; m++) {
    int slot = t * 8 + ((m + t) & 7);
    *(float4*)&hbuf[slot * 4] = make_float4(h[m * 4], h[m * 4 + 1], h[m * 4 + 2], h[m * 4 + 3]);
  }
  __syncthreads();
  float4* dst = (float4*)(newH + (size_t)cell0 * 32);
  #pragma unroll
  for (int m = 0; m < 8; m++) {
    int s = t + 256 * m;
    int cs = s >> 3, ms = s & 7;
    int slot = cs * 8 + ((ms + cs) & 7);
    dst[s] = *(const float4*)&hbuf[slot * 4];
  }
}

// ---------------------------------------------------------------------------
// Kernel 5: transpose+split newW (f32 [k][n]) -> Wt bf16 hi/lo [n][k]
// ---------------------------------------------------------------------------
__global__ __launch_bounds__(256) void k_wt(const float* __restrict__ nW,
                                            ushort* __restrict__ Wt) {
  __shared__ float buf[64][65];
  int t = threadIdx.x;
  int i0 = blockIdx.y * 64, j0 = blockIdx.x * 64;
  int jl = t & 63, rr = t >> 6;
  #pragma unroll
  for (int r2 = 0; r2 < 16; r2++) {
    int il = r2 * 4 + rr;
    buf[jl][il] = nW[(size_t)(i0 + il) * 1024 + j0 + jl];
  }
  __syncthreads();
  int jw = t >> 2, iq = (t & 3) * 16;
  ushort hi[16], lo[16];
  #pragma unroll
  for (int e = 0; e < 16; e++) {
    float x = buf[jw][iq + e];
    ushort h = bf16_rne(x);
    hi[e] = h;
    lo[e] = bf16_rne(x - bf16_tof(h));
  }
  size_t base = (size_t)(j0 + jw) * 1024 + i0 + iq;
  *(uint4*)(Wt + base)     = *(uint4*)hi;
  *(uint4*)(Wt + base + 8) = *(uint4*)(hi + 8);
  *(uint4*)(Wt + 1048576 + base)     = *(uint4*)lo;
  *(uint4*)(Wt + 1048576 + base + 8) = *(uint4*)(lo + 8);
}

// ---------------------------------------------------------------------------
// Kernel 6: MFMA GEMM  logits = X @ newW  via 3-term bf16 hi/lo split.
// No LDS: direct global->VGPR fragment loads (data is L2/L3-resident).
// Block = 64x64 C-tile, 4 waves each 32x32 (2x2 of 16x16x32 MFMA).
// A frag: lane row = m0+(l&15), k-octet = k0+8*(l>>4)   (16B contiguous)
// B frag: lane col = n0+(l&15), same k-octet, from Wt[n][k]
// ---------------------------------------------------------------------------
__global__ __launch_bounds__(256) void k_gemm(const ushort* __restrict__ Xb,
                                              const ushort* __restrict__ Wt,
                                              float* __restrict__ C) {
  int t = threadIdx.x;
  int w = t >> 6, l = t & 63;
  int m0 = blockIdx.y * 64 + (w >> 1) * 32;
  int n0 = blockIdx.x * 64 + (w & 1) * 32;
  int lr = l & 15;
  int kg = (l >> 4) * 8;
  const ushort* Xhi = Xb;
  const ushort* Xlo = Xb + 1048576;
  const ushort* Whi = Wt;
  const ushort* Wlo = Wt + 1048576;
  const size_t ra0 = (size_t)(m0 + lr) * 1024;
  const size_t ra1 = (size_t)(m0 + 16 + lr) * 1024;
  const size_t cb0 = (size_t)(n0 + lr) * 1024;
  const size_t cb1 = (size_t)(n0 + 16 + lr) * 1024;
  f32x4 acc00 = {0.f, 0.f, 0.f, 0.f};
  f32x4 acc01 = {0.f, 0.f, 0.f, 0.f};
  f32x4 acc10 = {0.f, 0.f, 0.f, 0.f};
  f32x4 acc11 = {0.f, 0.f, 0.f, 0.f};
  #pragma unroll 2
  for (int k0 = 0; k0 < 1024; k0 += 32) {
    int o = k0 + kg;
    bf16x8 ah0 = *(const bf16x8*)(Xhi + ra0 + o);
    bf16x8 ah1 = *(const bf16x8*)(Xhi + ra1 + o);
    bf16x8 al0 = *(const bf16x8*)(Xlo + ra0 + o);
    bf16x8 al1 = *(const bf16x8*)(Xlo + ra1 + o);
    bf16x8 bh0 = *(const bf16x8*)(Whi + cb0 + o);
    bf16x8 bh1 = *(const bf16x8*)(Whi + cb1 + o);
    bf16x8 bl0 = *(const bf16x8*)(Wlo + cb0 + o);
    bf16x8 bl1 = *(const bf16x8*)(Wlo + cb1 + o);
    acc00 = __builtin_amdgcn_mfma_f32_16x16x32_bf16(ah0, bh0, acc00, 0, 0, 0);
    acc01 = __builtin_amdgcn_mfma_f32_16x16x32_bf16(ah0, bh1, acc01, 0, 0, 0);
    acc10 = __builtin_amdgcn_mfma_f32_16x16x32_bf16(ah1, bh0, acc10, 0, 0, 0);
    acc11 = __builtin_amdgcn_mfma_f32_16x16x32_bf16(ah1, bh1, acc11, 0, 0, 0);
    acc00 = __builtin_amdgcn_mfma_f32_16x16x32_bf16(ah0, bl0, acc00, 0, 0, 0);
    acc01 = __builtin_amdgcn_mfma_f32_16x16x32_bf16(ah0, bl1, acc01, 0, 0, 0);
    acc10 = __builtin_amdgcn_mfma_f32_16x16x32_bf16(ah1, bl0, acc10, 0, 0, 0);
    acc11 = __builtin_amdgcn_mfma_f32_16x16x32_bf16(ah1, bl1, acc11, 0, 0, 0);
    acc00 = __builtin_amdgcn_mfma_f32_16x16x32_bf16(al0, bh0, acc00, 0, 0, 0);
    acc01 = __builtin_amdgcn_mfma_f32_16x16x32_bf16(al0, bh1, acc01, 0, 0, 0);
    acc10 = __builtin_amdgcn_mfma_f32_16x16x32_bf16(al1, bh0, acc10, 0, 0, 0);
    acc11 = __builtin_amdgcn_mfma_f32_16x16x32_bf16(al1, bh1, acc11, 0, 0, 0);
  }
  int rbase = m0 + (l >> 4) * 4;
  #pragma unroll
  for (int r = 0; r < 4; r++) {
    C[(size_t)(rbase + r) * 1024 + n0 + lr]           = acc00[r];
    C[(size_t)(rbase + r) * 1024 + n0 + 16 + lr]      = acc01[r];
    C[(size_t)(rbase + 16 + r) * 1024 + n0 + lr]      = acc10[r];
    C[(size_t)(rbase + 16 + r) * 1024 + n0 + 16 + lr] = acc11[r];
  }
}

// ---------------------------------------------------------------------------
// Kernel 7: row softmax
// ---------------------------------------------------------------------------
__global__ __launch_bounds__(256) void k_softmax(const float* __restrict__ L,
                                                 float* __restrict__ P) {
  __shared__ float sm[4], ss[4];
  int r = blockIdx.x, t = threadIdx.x;
  const float* row = L + r * 1024;
  float v0 = row[t], v1 = row[t + 256], v2 = row[t + 512], v3 = row[t + 768];
  float m = fmaxf(fmaxf(v0, v1), fmaxf(v2, v3));
  #pragma unroll
  for (int off = 32; off > 0; off >>= 1) m = fmaxf(m, __shfl_xor(m, off, 64));
  int wv = t >> 6, lane = t & 63;
  if (lane == 0) sm[wv] = m;
  __syncthreads();
  m = fmaxf(fmaxf(sm[0], sm[1]), fmaxf(sm[2], sm[3]));
  float e0 = expf(v0 - m), e1 = expf(v1 - m), e2 = expf(v2 - m), e3 = expf(v3 - m);
  float s = e0 + e1 + e2 + e3;
  #pragma unroll
  for (int off = 32; off > 0; off >>= 1) s += __shfl_xor(s, off, 64);
  if (lane == 0) ss[wv] = s;
  __syncthreads();
  s = ss[0] + ss[1] + ss[2] + ss[3];
  float inv = 1.0f / s;
  float* prow = P + r * 1024;
  prow[t] = e0 * inv; prow[t + 256] = e1 * inv;
  prow[t + 512] = e2 * inv; prow[t + 768] = e3 * inv;
}

extern "C" void kernel_launch(void* const* d_in, const int* in_sizes, int n_in,
                              void* d_out, int out_size, void* d_ws, size_t ws_size,
                              hipStream_t stream) {
  const float* X  = (const float*)d_in[0];
  const float* W  = (const float*)d_in[1];
  const float* Hd = (const float*)d_in[2];
  const float* W1 = (const float*)d_in[3];
  const float* b1 = (const float*)d_in[4];
  const float* W2 = (const float*)d_in[5];
  const float* b2 = (const float*)d_in[6];
  const float* W3 = (const float*)d_in[7];
  const float* b3 = (const float*)d_in[8];
  float* out   = (float*)d_out;
  float* probs = out;
  float* newW  = out + 1024 * 1024;
  float* newH  = out + 2 * 1024 * 1024;
  float* ws = (float*)d_ws;

  // npart: largest in {8..64} such that HPART + XB(1M f32) + WT(1M f32) fit.
  size_t wsf = ws_size / 4;
  int npart = 64;
  while (npart > 8 &&
         (size_t)WS_HPART + (size_t)npart * 32768ull + 2097152ull > wsf)
    npart >>= 1;
  float*  rhpart = ws + WS_RHP;
  float*  wcp    = ws + WS_WCP;
  float*  hpart  = ws + WS_HPART;
  size_t  xb0    = (size_t)WS_HPART + (size_t)npart * 32768ull;
  ushort* Xb     = (ushort*)(ws + xb0);
  ushort* Wt     = (ushort*)(ws + xb0 + 1048576);

  k_red1<<<npart * 8, 512, 0, stream>>>(Hd, hpart, rhpart, npart);
  k_wred<<<656, 256, 0, stream>>>(W, X, ws, wcp, Xb);
  k_red2pq<<<133, 256, 0, stream>>>(hpart, wcp, rhpart, W1, b1, W2, b2, W3, b3,
                                    ws, npart);
  k_mlp<<<4096, 256, 0, stream>>>(W, Hd, ws, newW, newH);
  k_wt<<<dim3(16, 16), 256, 0, stream>>>(newW, Wt);
  k_gemm<<<dim3(16, 16), 256, 0, stream>>>(Xb, Wt, ws + WS_LOGITS);
  k_softmax<<<1024, 256, 0, stream>>>(ws + WS_LOGITS, probs);
}